// Round 6
// baseline (126.305 us; speedup 1.0000x reference)
//
#include <hip/hip_runtime.h>

// Static shapes: B=16, T=512, D=384 (=96 float4), F=max_len=4096.
#define BB   16
#define TT   512
#define FF   4096
#define DD4  96
#define FPT  16                  // frames per gather block
#define TILES (FF / FPT)         // 256 tiles per batch
#define NTHR 256

// Native 4-float vector: __builtin_nontemporal_store rejects HIP's float4
// wrapper class but accepts ext_vector_type. Same 16 B layout.
typedef float floatx4 __attribute__((ext_vector_type(4)));

// Kernel 1 (R1-proven, verbatim): one block per batch. Hillis-Steele LDS scan
// of durations, then scatter phoneme index t into fidx[cum-d .. cum).
// Frames past the total stay -1 (zero-fill in gather).
__global__ __launch_bounds__(TT) void build_idx_kernel(
    const int* __restrict__ dur, int* __restrict__ fidx) {
    const int b = blockIdx.x;
    const int t = threadIdx.x;
    int* fb = fidx + b * FF;

#pragma unroll
    for (int k = 0; k < FF / TT; ++k) fb[k * TT + t] = -1;

    __shared__ int s[TT];
    const int d = dur[b * TT + t];
    s[t] = d;
    __syncthreads();
#pragma unroll
    for (int off = 1; off < TT; off <<= 1) {
        int v = (t >= off) ? s[t - off] : 0;
        __syncthreads();
        s[t] += v;
        __syncthreads();
    }
    const int cum = s[t];            // inclusive cumsum
    const int start = cum - d;
    const int end = cum < FF ? cum : FF;   // max total = 512*7 = 3584 < 4096
    for (int f = start; f < end; ++f) fb[f] = t;
}

// Kernel 2: gather v2. Position-contiguous layout: pos = k*256 + t covers
// 16 frames * 96 float4 = 1536 float4 contiguously -> each wave64 store is one
// 1024 B contiguous segment. No LDS, no barriers. fidx loads hit L1 (6 x 4 B
// per thread). Output stores are nontemporal (write-only stream; keep x in L2).
__global__ __launch_bounds__(NTHR) void gather_kernel(
    const floatx4* __restrict__ x, const int* __restrict__ fidx,
    floatx4* __restrict__ out) {
    const int bid  = blockIdx.x;
    const int b    = bid / TILES;
    const int tile = bid - b * TILES;
    const int f0   = tile * FPT;
    const int t    = threadIdx.x;

    const floatx4* xb = x + (size_t)b * TT * DD4;
    const int* fb = fidx + b * FF + f0;
    floatx4* ob = out + ((size_t)b * FF + f0) * DD4;

#pragma unroll
    for (int k = 0; k < (FPT * DD4) / NTHR; ++k) {   // 6 iterations
        const int pos = k * NTHR + t;
        const int fl  = pos / DD4;                   // frame within tile
        const int c   = pos - fl * DD4;              // float4 column
        const int idx = fb[fl];                      // L1 broadcast
        floatx4 vv;
        if (idx >= 0) {
            vv = xb[(size_t)idx * DD4 + c];
        } else {
            vv = (floatx4)(0.f);
        }
        __builtin_nontemporal_store(vv, ob + pos);
    }
}

extern "C" void kernel_launch(void* const* d_in, const int* in_sizes, int n_in,
                              void* d_out, int out_size, void* d_ws, size_t ws_size,
                              hipStream_t stream) {
    const float* x = (const float*)d_in[0];
    const int* dur = (const int*)d_in[1];   // int32 on device
    int* fidx = (int*)d_ws;                 // B*F ints = 256 KB scratch

    build_idx_kernel<<<BB, TT, 0, stream>>>(dur, fidx);
    gather_kernel<<<BB * TILES, NTHR, 0, stream>>>(
        (const floatx4*)x, fidx, (floatx4*)d_out);
}

// Round 7
// 119.260 us; speedup vs baseline: 1.0591x; 1.0591x over previous
//
#include <hip/hip_runtime.h>

// Static shapes: B=16, T=512, D=384 (=96 float4), F=max_len=4096.
#define BB   16
#define TT   512
#define FF   4096
#define DD4  96
#define FPT  16                  // frames per gather block
#define TILES (FF / FPT)         // 256 tiles per batch
#define NTHR 256

// Kernel 1 (R1-proven, verbatim): one block per batch. Hillis-Steele LDS scan
// of durations, then scatter phoneme index t into fidx[cum-d .. cum).
// Frames past the total stay -1 (zero-fill in gather).
__global__ __launch_bounds__(TT) void build_idx_kernel(
    const int* __restrict__ dur, int* __restrict__ fidx) {
    const int b = blockIdx.x;
    const int t = threadIdx.x;
    int* fb = fidx + b * FF;

#pragma unroll
    for (int k = 0; k < FF / TT; ++k) fb[k * TT + t] = -1;

    __shared__ int s[TT];
    const int d = dur[b * TT + t];
    s[t] = d;
    __syncthreads();
#pragma unroll
    for (int off = 1; off < TT; off <<= 1) {
        int v = (t >= off) ? s[t - off] : 0;
        __syncthreads();
        s[t] += v;
        __syncthreads();
    }
    const int cum = s[t];            // inclusive cumsum
    const int start = cum - d;
    const int end = cum < FF ? cum : FF;   // max total = 512*7 = 3584 < 4096
    for (int f = start; f < end; ++f) fb[f] = t;
}

// Kernel 2 (R4-proven, best measured: 117.7 us): thread t owns frame (t>>4),
// columns (t&15)+16k. One fidx load per thread (L1 broadcast x16), no LDS, no
// barriers, 6 independent float4 load/store pairs. Every load and store is a
// clean 256 B contiguous segment per 16 lanes.
// NOTE (R6 post-mortem): nontemporal stores REGRESSED (+8.6 us) — normal
// cached stores drain faster on gfx950. Keep plain stores.
__global__ __launch_bounds__(NTHR) void gather_kernel(
    const float4* __restrict__ x, const int* __restrict__ fidx,
    float4* __restrict__ out) {
    const int bid  = blockIdx.x;
    const int b    = bid / TILES;
    const int tile = bid - b * TILES;
    const int t    = threadIdx.x;
    const int fl   = t >> 4;               // frame within tile, 0..15
    const int c0   = t & 15;               // column group
    const int f    = tile * FPT + fl;

    const int idx = fidx[b * FF + f];
    float4* dst = out + ((size_t)b * FF + f) * DD4;

    if (idx >= 0) {
        const float4* src = x + ((size_t)b * TT + idx) * DD4;
#pragma unroll
        for (int k = 0; k < 6; ++k) dst[c0 + 16 * k] = src[c0 + 16 * k];
    } else {
        const float4 z = make_float4(0.f, 0.f, 0.f, 0.f);
#pragma unroll
        for (int k = 0; k < 6; ++k) dst[c0 + 16 * k] = z;
    }
}

extern "C" void kernel_launch(void* const* d_in, const int* in_sizes, int n_in,
                              void* d_out, int out_size, void* d_ws, size_t ws_size,
                              hipStream_t stream) {
    const float* x = (const float*)d_in[0];
    const int* dur = (const int*)d_in[1];   // int32 on device
    int* fidx = (int*)d_ws;                 // B*F ints = 256 KB scratch

    build_idx_kernel<<<BB, TT, 0, stream>>>(dur, fidx);
    gather_kernel<<<BB * TILES, NTHR, 0, stream>>>(
        (const float4*)x, fidx, (float4*)d_out);
}